// Round 13
// baseline (9815.072 us; speedup 1.0000x reference)
//
#include <hip/hip_runtime.h>
#include <cstdint>
#include <cstddef>

// ---------- small helpers ----------
typedef __bf16 bf16x8 __attribute__((ext_vector_type(8)));
typedef float  f32x4  __attribute__((ext_vector_type(4)));
typedef _Float16 h8 __attribute__((ext_vector_type(8)));

union UF { uint4 u; h8 h; };

__device__ __forceinline__ float b2f(unsigned short u) {
    union { uint32_t i; float f; } x; x.i = ((uint32_t)u) << 16; return x.f;
}
__device__ __forceinline__ unsigned short f2bf(float f) {
    uint32_t u = __float_as_uint(f);
    uint32_t r = (u + 0x7FFFu + ((u >> 16) & 1u)) >> 16;   // RNE, no NaN in data
    return (unsigned short)r;
}
__device__ __forceinline__ uint32_t packf16(float a, float b) {
    union { _Float16 h[2]; uint32_t u; } x;
    x.h[0] = (_Float16)a; x.h[1] = (_Float16)b; return x.u;
}
__device__ __forceinline__ unsigned short f16b(float f) {
    union { _Float16 h; unsigned short u; } x; x.h = (_Float16)f; return x.u;
}

// JAX threefry2x32 (20 rounds), usable host+device
__host__ __device__ inline void tf2x32(uint32_t k0, uint32_t k1,
                                       uint32_t x0, uint32_t x1,
                                       uint32_t& o0, uint32_t& o1) {
    uint32_t ks2 = k0 ^ k1 ^ 0x1BD11BDAu;
#define TF_ROT(x,n) (((x) << (n)) | ((x) >> (32 - (n))))
#define TF_RND(r) { x0 += x1; x1 = TF_ROT(x1, r); x1 ^= x0; }
    x0 += k0; x1 += k1;
    TF_RND(13) TF_RND(15) TF_RND(26) TF_RND(6)
    x0 += k1; x1 += ks2 + 1u;
    TF_RND(17) TF_RND(29) TF_RND(16) TF_RND(24)
    x0 += ks2; x1 += k0 + 2u;
    TF_RND(13) TF_RND(15) TF_RND(26) TF_RND(6)
    x0 += k0; x1 += k1 + 3u;
    TF_RND(17) TF_RND(29) TF_RND(16) TF_RND(24)
    x0 += k1; x1 += ks2 + 4u;
    TF_RND(13) TF_RND(15) TF_RND(26) TF_RND(6)
    x0 += ks2; x1 += k0 + 5u;
    o0 = x0; o1 = x1;
#undef TF_RND
#undef TF_ROT
}

// ---------- constants ----------
#define BATCH 32
#define TSAMP 524288
#define FRAMES 1024
#define HID 256
#define GATES 1024            // 4*HID
#define MROWS 32768           // BATCH*FRAMES
#define NCLS 29
#define NMASK 16777216u       // 32*1024*512
#define TCH 256               // time chunk
#define NCHUNK 4

// ---------- stats: per-batch mean / 1/(std+eps) ----------
__global__ __launch_bounds__(256) void k_stats1(const float* __restrict__ sig,
                                                float* __restrict__ psum,
                                                float* __restrict__ psq) {
    int blk = blockIdx.x;               // 1024 blocks, 32 per batch
    int tid = threadIdx.x;
    size_t base = (size_t)blk * 16384;
    float s = 0.f, q = 0.f;
    for (int i = 0; i < 16; ++i) {
        float4 v = *reinterpret_cast<const float4*>(sig + base + ((size_t)i * 256 + tid) * 4);
        s += v.x + v.y + v.z + v.w;
        q += v.x * v.x + v.y * v.y + v.z * v.z + v.w * v.w;
    }
    __shared__ float ls[4], lq[4];
    int w = tid >> 6, lane = tid & 63;
    for (int m = 32; m; m >>= 1) { s += __shfl_down(s, m); q += __shfl_down(q, m); }
    if (lane == 0) { ls[w] = s; lq[w] = q; }
    __syncthreads();
    if (tid == 0) {
        psum[blk] = ls[0] + ls[1] + ls[2] + ls[3];
        psq[blk]  = lq[0] + lq[1] + lq[2] + lq[3];
    }
}

__global__ __launch_bounds__(1024) void k_stats2(const float* __restrict__ psum,
                                                 const float* __restrict__ psq,
                                                 float* __restrict__ mu,
                                                 float* __restrict__ rstd) {
    int tid = threadIdx.x;              // 1024 = 32 batches * 32 chunks
    float s = psum[tid], q = psq[tid];
    for (int m = 16; m; m >>= 1) { s += __shfl_down(s, m); q += __shfl_down(q, m); }
    if ((tid & 31) == 0) {
        int b = tid >> 5;
        float m_ = s * (1.f / (float)TSAMP);
        float v  = q * (1.f / (float)TSAMP) - m_ * m_;
        float sd = sqrtf(fmaxf(v, 0.f));
        mu[b] = m_;
        rstd[b] = 1.f / (sd + 1e-8f);
    }
}

// ---------- normalize + frame -> bf16 hi/lo pair [32768][512] ----------
__global__ __launch_bounds__(256) void k_norm(const float* __restrict__ sig,
                                              const float* __restrict__ mu,
                                              const float* __restrict__ rstd,
                                              unsigned short* __restrict__ xh,
                                              unsigned short* __restrict__ xl) {
    size_t gid = (size_t)blockIdx.x * 256 + threadIdx.x;   // 4194304 threads, 4 elems each
    int b = (int)(gid >> 17);
    float m = mu[b], r = rstd[b];
    float4 v = *reinterpret_cast<const float4*>(sig + gid * 4);
    float f0 = (v.x - m) * r, f1 = (v.y - m) * r, f2 = (v.z - m) * r, f3 = (v.w - m) * r;
    ushort4 oh, ol;
    oh.x = f2bf(f0); ol.x = f2bf(f0 - b2f(oh.x));
    oh.y = f2bf(f1); ol.y = f2bf(f1 - b2f(oh.y));
    oh.z = f2bf(f2); ol.z = f2bf(f2 - b2f(oh.z));
    oh.w = f2bf(f3); ol.w = f2bf(f3 - b2f(oh.w));
    *reinterpret_cast<ushort4*>(xh + gid * 4) = oh;
    *reinterpret_cast<ushort4*>(xl + gid * 4) = ol;
}

// ---------- weight prep: Wih transpose + hi/lo split ----------
__global__ __launch_bounds__(256) void k_wih_t(const float* __restrict__ Wih,
                                               unsigned short* __restrict__ WTh,
                                               unsigned short* __restrict__ WTl) {
    size_t gid = (size_t)blockIdx.x * 256 + threadIdx.x;   // 3145728
    int k = (int)(gid & 511);
    int n = (int)((gid >> 9) & 1023);
    int ld = (int)(gid >> 19);
    float w = Wih[((size_t)ld * 512 + k) * 1024 + n];
    unsigned short h = f2bf(w);
    WTh[gid] = h;
    WTl[gid] = f2bf(w - b2f(h));
}

// ---------- weight prep: Whh -> MFMA B-fragments, fp16 ----------
// Wfr dword index = ((ld*512 + frag)*64 + lane)*4 + j;  frag = nt*8 + kt.
// B layout for mfma_f32_16x16x32_f16 (verified by round-0 GEMM):
//   lane holds B[k = kt*32 + (lane>>4)*8 + jj][col = nt*16 + (lane&15)], jj = 0..7;
//   dword j packs (jj=2j, 2j+1) as (low, high) fp16.
__global__ __launch_bounds__(256) void k_wfrag(const float* __restrict__ W,
                                               uint32_t* __restrict__ Wfr) {
    uint32_t gid = blockIdx.x * 256u + threadIdx.x;        // 786432
    int j    = (int)(gid & 3);
    int lane = (int)((gid >> 2) & 63);
    int frag = (int)((gid >> 8) & 511);
    int ld   = (int)(gid >> 17);
    int nt = frag >> 3, kt = frag & 7;
    int col = nt * 16 + (lane & 15);
    int k0  = kt * 32 + (lane >> 4) * 8 + 2 * j;
    const float* base = W + (size_t)ld * 256 * 1024;
    Wfr[gid] = packf16(base[(size_t)k0 * 1024 + col],
                       base[(size_t)(k0 + 1) * 1024 + col]);
}

// ---------- chunked input GEMM (split-bf16 MFMA, fp32 out) ----------
__global__ __launch_bounds__(256) void k_gemm_chunk(const unsigned short* __restrict__ Ah,
                                                    const unsigned short* __restrict__ Al,
                                                    const unsigned short* __restrict__ BTh,
                                                    const unsigned short* __restrict__ BTl,
                                                    float* __restrict__ C,
                                                    int t0) {
    __shared__ __align__(16) unsigned short Ahs[128][40];
    __shared__ __align__(16) unsigned short Als[128][40];
    __shared__ __align__(16) unsigned short Bhs[128][40];
    __shared__ __align__(16) unsigned short Bls[128][40];
    const int tid = threadIdx.x;
    const int tm = blockIdx.y * 128;     // gridDim.y = 64  (8192 chunk rows)
    const int tn = blockIdx.x * 128;     // gridDim.x = 8   (1024 gate cols)
    const int lane = tid & 63, w = tid >> 6;
    const int wr = w >> 1, wc = w & 1;
    const int l15 = lane & 15, lk = (lane >> 4) * 8;
    f32x4 acc[4][4];
    for (int i = 0; i < 4; ++i)
        for (int j = 0; j < 4; ++j)
            acc[i][j] = (f32x4){0.f, 0.f, 0.f, 0.f};
    const int srow = tid >> 1, scol = (tid & 1) * 16;
    const int rg = tm + srow;
    const size_t am = (size_t)((rg >> 8) * 1024 + t0 + (rg & 255)) * 512;
    const size_t bm = (size_t)(tn + srow) * 512;
    for (int kt = 0; kt < 512; kt += 32) {
        *reinterpret_cast<uint4*>(&Ahs[srow][scol])     = *reinterpret_cast<const uint4*>(&Ah[am + kt + scol]);
        *reinterpret_cast<uint4*>(&Ahs[srow][scol + 8]) = *reinterpret_cast<const uint4*>(&Ah[am + kt + scol + 8]);
        *reinterpret_cast<uint4*>(&Als[srow][scol])     = *reinterpret_cast<const uint4*>(&Al[am + kt + scol]);
        *reinterpret_cast<uint4*>(&Als[srow][scol + 8]) = *reinterpret_cast<const uint4*>(&Al[am + kt + scol + 8]);
        *reinterpret_cast<uint4*>(&Bhs[srow][scol])     = *reinterpret_cast<const uint4*>(&BTh[bm + kt + scol]);
        *reinterpret_cast<uint4*>(&Bhs[srow][scol + 8]) = *reinterpret_cast<const uint4*>(&BTh[bm + kt + scol + 8]);
        *reinterpret_cast<uint4*>(&Bls[srow][scol])     = *reinterpret_cast<const uint4*>(&BTl[bm + kt + scol]);
        *reinterpret_cast<uint4*>(&Bls[srow][scol + 8]) = *reinterpret_cast<const uint4*>(&BTl[bm + kt + scol + 8]);
        __syncthreads();
        bf16x8 afh[4], afl[4], bfh[4], bfl[4];
        for (int m = 0; m < 4; ++m) {
            afh[m] = *reinterpret_cast<const bf16x8*>(&Ahs[wr * 64 + m * 16 + l15][lk]);
            afl[m] = *reinterpret_cast<const bf16x8*>(&Als[wr * 64 + m * 16 + l15][lk]);
        }
        for (int n = 0; n < 4; ++n) {
            bfh[n] = *reinterpret_cast<const bf16x8*>(&Bhs[wc * 64 + n * 16 + l15][lk]);
            bfl[n] = *reinterpret_cast<const bf16x8*>(&Bls[wc * 64 + n * 16 + l15][lk]);
        }
        for (int m = 0; m < 4; ++m)
            for (int n = 0; n < 4; ++n) {
                acc[m][n] = __builtin_amdgcn_mfma_f32_16x16x32_bf16(afh[m], bfh[n], acc[m][n], 0, 0, 0);
                acc[m][n] = __builtin_amdgcn_mfma_f32_16x16x32_bf16(afl[m], bfh[n], acc[m][n], 0, 0, 0);
                acc[m][n] = __builtin_amdgcn_mfma_f32_16x16x32_bf16(afh[m], bfl[n], acc[m][n], 0, 0, 0);
            }
        __syncthreads();
    }
    const int rbase = tm + wr * 64 + (lane >> 4) * 4;
    const int cbase = tn + wc * 64 + l15;
    for (int m = 0; m < 4; ++m)
        for (int n = 0; n < 4; ++n)
            for (int r = 0; r < 4; ++r) {
                int row = rbase + m * 16 + r;
                int col = cbase + n * 16;
                C[(size_t)row * 1024 + col] = acc[m][n][r];
            }
}

// ---------- LSTM scan: one block per (dir,batch); MFMA dot, weights on-chip ----------
// 512 threads (8 waves, 2/SIMD -> 256-reg budget). Wave w owns n-tiles 8w..8w+7.
// Per (nt,kt) fragment tiering: kt0..3 in 32 half8 REGS (128 regs; MFMA reads them
// in place -- no accvgpr_read, no remat pressure since ~210 < 256 cap);
// kt4..5 in LDS (128 KB, b128 conflict-free); kt6..7 streamed (128 KB/step,
// 1-nt lookahead; `zo` opaque offset defeats LICM hoist -> spill).
// M=1: h occupies A row 0 (lanes 0,16,32,48); C row 0 = lanes 0..15 reg 0.
__global__ __launch_bounds__(512) void k_scan7(const uint32_t* __restrict__ Wfr,  // [ld][512 frag][64 lane][4]
                                               const float* __restrict__ bias,
                                               const float* __restrict__ xgA,    // fwd [32][256][1024]
                                               const float* __restrict__ xgB,    // bwd [32][256][1024]
                                               float* __restrict__ hout,
                                               float* __restrict__ hstate,       // [64][256]
                                               float* __restrict__ cstate,       // [64][256]
                                               int layer, int chunk) {
    const int g = blockIdx.x;                   // 0..63
    const int d = g >> 5, b = g & 31;
    const int tid = threadIdx.x;                // 0..511
    const int lane = tid & 63, w = tid >> 6;
    const int ld = layer * 2 + d;

    __shared__ __align__(16) uint32_t Wl[128 * 256];        // 128 KB: LDS frags kt4..5
    __shared__ __align__(16) float gbuf[GATES];             // 4 KB raw gate pre-acts
    __shared__ __align__(16) unsigned short hh[HID];        // h as fp16, 512 B

    const uint32_t* Wb = Wfr + (size_t)ld * 512 * 256;

    // ---- stage LDS frags: slot s = nt*2 + (kt-4) ----
    for (int idx = tid; idx < 128 * 256; idx += 512) {
        int s = idx >> 8, dw = idx & 255;
        int nt = s >> 1, kt = 4 + (s & 1);
        Wl[idx] = Wb[(size_t)(nt * 8 + kt) * 256 + dw];
    }
    // ---- register frags: kt 0..3 of my wave's 8 n-tiles (32 x half8 = 128 regs) ----
    h8 wag[32];
    #pragma unroll
    for (int n = 0; n < 8; ++n)
        #pragma unroll
        for (int kt = 0; kt < 4; ++kt) {
            UF t;
            t.u = *reinterpret_cast<const uint4*>(Wb + (size_t)((w * 8 + n) * 8 + kt) * 256 + lane * 4);
            wag[n * 4 + kt] = t.h;
        }

    float b0 = 0.f, b1 = 0.f, b2 = 0.f, b3 = 0.f, creg = 0.f, hreg = 0.f;
    if (tid < HID) {
        b0 = bias[(size_t)ld * 1024 + tid];
        b1 = bias[(size_t)ld * 1024 + 256 + tid];
        b2 = bias[(size_t)ld * 1024 + 512 + tid];
        b3 = bias[(size_t)ld * 1024 + 768 + tid];
        if (chunk != 0) {
            hreg = hstate[(size_t)g * 256 + tid];
            creg = cstate[(size_t)g * 256 + tid];
        }
        hh[tid] = f16b(hreg);
    }
    __syncthreads();

    const float* xbase = (d ? xgB : xgA) + (size_t)b * TCH * 1024;
    const int tl0 = d ? (TCH - 1) : 0, tstep = d ? -1 : 1;

    for (int sl = 0; sl < TCH; ++sl) {
        const int tloc = tl0 + tstep * sl;
        // current-step xg: issued first, consumed after the dot phase (latency covered)
        float x0 = 0.f, x1 = 0.f, x2 = 0.f, x3 = 0.f;
        if (tid < HID) {
            const float* xr = xbase + (size_t)tloc * 1024 + tid;
            x0 = xr[0]; x1 = xr[256]; x2 = xr[512]; x3 = xr[768];
        }
        uint32_t zo = 0;
        asm volatile("" : "+v"(zo));          // opaque 0: keep weight loads inside the loop

        // A fragments: h row 0 (lanes 0,16,32,48 carry k-slices)
        uint4 afu[8];
        #pragma unroll
        for (int kt = 0; kt < 8; ++kt) {
            uint4 v; v.x = v.y = v.z = v.w = 0u;
            if ((lane & 15) == 0)
                v = *reinterpret_cast<const uint4*>(&hh[kt * 32 + (lane >> 4) * 8]);
            afu[kt] = v;
        }

        // stream prologue: n-tile 0's kt6,7
        uint4 s6 = *reinterpret_cast<const uint4*>(Wb + (size_t)((w * 8 + 0) * 8 + 6) * 256 + lane * 4 + zo);
        uint4 s7 = *reinterpret_cast<const uint4*>(Wb + (size_t)((w * 8 + 0) * 8 + 7) * 256 + lane * 4 + zo);

        #pragma unroll
        for (int n = 0; n < 8; ++n) {
            uint4 t6 = s6, t7 = s7;
            if (n < 7) {
                t6 = *reinterpret_cast<const uint4*>(Wb + (size_t)((w * 8 + n + 1) * 8 + 6) * 256 + lane * 4 + zo);
                t7 = *reinterpret_cast<const uint4*>(Wb + (size_t)((w * 8 + n + 1) * 8 + 7) * 256 + lane * 4 + zo);
            }
            f32x4 acc = (f32x4){0.f, 0.f, 0.f, 0.f};
            #pragma unroll
            for (int kt = 0; kt < 4; ++kt) {
                UF a; a.u = afu[kt];
                acc = __builtin_amdgcn_mfma_f32_16x16x32_f16(a.h, wag[n * 4 + kt], acc, 0, 0, 0);
            }
            {
                int s = (w * 8 + n) * 2;
                UF a4; a4.u = afu[4];
                UF w4; w4.u = *reinterpret_cast<const uint4*>(&Wl[(size_t)s * 256 + lane * 4 + zo]);
                acc = __builtin_amdgcn_mfma_f32_16x16x32_f16(a4.h, w4.h, acc, 0, 0, 0);
                UF a5; a5.u = afu[5];
                UF w5; w5.u = *reinterpret_cast<const uint4*>(&Wl[(size_t)(s + 1) * 256 + lane * 4 + zo]);
                acc = __builtin_amdgcn_mfma_f32_16x16x32_f16(a5.h, w5.h, acc, 0, 0, 0);
            }
            {
                UF a6; a6.u = afu[6]; UF w6; w6.u = s6;
                acc = __builtin_amdgcn_mfma_f32_16x16x32_f16(a6.h, w6.h, acc, 0, 0, 0);
                UF a7; a7.u = afu[7]; UF w7; w7.u = s7;
                acc = __builtin_amdgcn_mfma_f32_16x16x32_f16(a7.h, w7.h, acc, 0, 0, 0);
            }
            if (lane < 16) gbuf[(w * 8 + n) * 16 + lane] = acc[0];  // C row0 = lanes 0..15, reg0
            s6 = t6; s7 = t7;
        }
        __syncthreads();

        if (tid < HID) {
            float gi = gbuf[tid]       + b0 + x0;
            float gf = gbuf[256 + tid] + b1 + x1;
            float gg = gbuf[512 + tid] + b2 + x2;
            float go = gbuf[768 + tid] + b3 + x3;
            float si = 1.f / (1.f + expf(-gi));
            float sf = 1.f / (1.f + expf(-gf));
            float so = 1.f / (1.f + expf(-go));
            creg = sf * creg + si * tanhf(gg);
            hreg = so * tanhf(creg);
            hh[tid] = f16b(hreg);
            const int sgl = chunk * TCH + sl;
            const int tg = d ? (FRAMES - 1 - sgl) : sgl;
            hout[((size_t)(d * BATCH + b) * FRAMES + tg) * HID + tid] = hreg;
        }
        __syncthreads();
    }
    if (tid < HID) {
        hstate[(size_t)g * 256 + tid] = hreg;
        cstate[(size_t)g * 256 + tid] = creg;
    }
}

// ---------- dropout(0.5) + ReLU + concat, JAX partitionable threefry ----------
__global__ __launch_bounds__(256) void k_dropout(const float* __restrict__ h,
                                                 unsigned short* __restrict__ xh,  // may be null
                                                 unsigned short* __restrict__ xl,  // may be null
                                                 float* __restrict__ xf,           // may be null
                                                 uint32_t fk0, uint32_t fk1) {
    uint32_t i = blockIdx.x * 256u + threadIdx.x;    // grid 65536 -> NMASK threads
    uint32_t o0, o1;
    tf2x32(fk0, fk1, 0u, i, o0, o1);
    uint32_t bits = o0 ^ o1;
    uint32_t f = i & 511u;
    uint32_t t = (i >> 9) & 1023u;
    uint32_t b = i >> 19;                            // 0..31
    uint32_t dv = f >> 8, n = f & 255u;
    float v = h[(((size_t)dv * BATCH + b) * FRAMES + t) * HID + n];
    float o = (((bits >> 31) == 0u) && v > 0.f) ? 2.f * v : 0.f;
    if (xh != nullptr) {
        unsigned short hb_ = f2bf(o);
        xh[i] = hb_;
        xl[i] = f2bf(o - b2f(hb_));
    }
    if (xf != nullptr) xf[i] = o;
}

// ---------- output projection: out[32768][29] = Xf[32768][512] @ Wout + bout ----------
__global__ __launch_bounds__(256) void k_out(const float* __restrict__ xf,
                                             const float* __restrict__ Wout,
                                             const float* __restrict__ bout,
                                             float* __restrict__ out) {
    __shared__ __align__(16) float Xs[64][68];
    const int tid = threadIdx.x;
    const int r = tid & 63, cg = tid >> 6;           // 4 col-groups of 8 (last has 5)
    const int row0 = blockIdx.x * 64;
    float acc[8] = {0.f, 0.f, 0.f, 0.f, 0.f, 0.f, 0.f, 0.f};
    for (int kc = 0; kc < 512; kc += 64) {
        int sr = tid >> 2, sc = (tid & 3) * 16;
        const float* src = xf + (size_t)(row0 + sr) * 512 + kc + sc;
        *reinterpret_cast<float4*>(&Xs[sr][sc])      = *reinterpret_cast<const float4*>(src);
        *reinterpret_cast<float4*>(&Xs[sr][sc + 4])  = *reinterpret_cast<const float4*>(src + 4);
        *reinterpret_cast<float4*>(&Xs[sr][sc + 8])  = *reinterpret_cast<const float4*>(src + 8);
        *reinterpret_cast<float4*>(&Xs[sr][sc + 12]) = *reinterpret_cast<const float4*>(src + 12);
        __syncthreads();
        for (int k = 0; k < 64; ++k) {
            float xv = Xs[r][k];
            const float* wr = Wout + (size_t)(kc + k) * NCLS + cg * 8;
            #pragma unroll
            for (int cc = 0; cc < 8; ++cc)
                if (cg * 8 + cc < NCLS) acc[cc] = fmaf(xv, wr[cc], acc[cc]);
        }
        __syncthreads();
    }
    for (int cc = 0; cc < 8; ++cc) {
        int col = cg * 8 + cc;
        if (col < NCLS) out[(size_t)(row0 + r) * NCLS + col] = acc[cc] + bout[col];
    }
}

// ---------- launch ----------
extern "C" void kernel_launch(void* const* d_in, const int* in_sizes, int n_in,
                              void* d_out, int out_size, void* d_ws, size_t ws_size,
                              hipStream_t stream) {
    const float* sig  = (const float*)d_in[0];
    const float* Wih  = (const float*)d_in[1];
    const float* Whh  = (const float*)d_in[2];
    const float* bias = (const float*)d_in[3];
    const float* Wout = (const float*)d_in[4];
    const float* bout = (const float*)d_in[5];
    float* out = (float*)d_out;

    char* ws = (char*)d_ws;
    size_t off = 0;
    auto alloc = [&](size_t bytes) -> void* {
        void* p = ws + off;
        off += (bytes + 255) & ~(size_t)255;
        return p;
    };
    float* psum           = (float*)alloc(1024 * 4);
    float* psq            = (float*)alloc(1024 * 4);
    float* mu             = (float*)alloc(32 * 4);
    float* rstd           = (float*)alloc(32 * 4);
    unsigned short* WThi  = (unsigned short*)alloc((size_t)6 * 1024 * 512 * 2);     // 6.3 MB
    unsigned short* WTlo  = (unsigned short*)alloc((size_t)6 * 1024 * 512 * 2);     // 6.3 MB
    uint32_t* Wfr         = (uint32_t*)alloc((size_t)6 * 512 * 256 * 4);            // 3.1 MB
    unsigned short* xhi   = (unsigned short*)alloc((size_t)MROWS * 512 * 2);        // 33.5 MB
    unsigned short* xlo   = (unsigned short*)alloc((size_t)MROWS * 512 * 2);        // 33.5 MB
    float* xgA            = (float*)alloc((size_t)BATCH * TCH * 1024 * 4);          // 33.5 MB
    float* xgB            = (float*)alloc((size_t)BATCH * TCH * 1024 * 4);          // 33.5 MB
    float* hb             = (float*)alloc((size_t)2 * BATCH * FRAMES * HID * 4);    // 67 MB
    float* hstate         = (float*)alloc((size_t)64 * HID * 4);
    float* cstate         = (float*)alloc((size_t)64 * HID * 4);
    // Total ~218 MB (proven layout).
    float* xf32           = (float*)xhi;   // layer-2 fp32 activations overlay dead xhi/xlo

    k_stats1<<<1024, 256, 0, stream>>>(sig, psum, psq);
    k_stats2<<<1, 1024, 0, stream>>>(psum, psq, mu, rstd);
    k_norm<<<16384, 256, 0, stream>>>(sig, mu, rstd, xhi, xlo);
    k_wih_t<<<12288, 256, 0, stream>>>(Wih, WThi, WTlo);
    k_wfrag<<<3072, 256, 0, stream>>>(Whh, Wfr);

    for (int l = 0; l < 3; ++l) {
        const unsigned short* Bh0 = WThi + (size_t)(l * 2 + 0) * 1024 * 512;
        const unsigned short* Bl0 = WTlo + (size_t)(l * 2 + 0) * 1024 * 512;
        const unsigned short* Bh1 = WThi + (size_t)(l * 2 + 1) * 1024 * 512;
        const unsigned short* Bl1 = WTlo + (size_t)(l * 2 + 1) * 1024 * 512;
        for (int c = 0; c < NCHUNK; ++c) {
            dim3 gg(8, 64);
            int t0f = c * TCH;
            int t0b = (NCHUNK - 1 - c) * TCH;
            k_gemm_chunk<<<gg, 256, 0, stream>>>(xhi, xlo, Bh0, Bl0, xgA, t0f);
            k_gemm_chunk<<<gg, 256, 0, stream>>>(xhi, xlo, Bh1, Bl1, xgB, t0b);
            k_scan7<<<64, 512, 0, stream>>>(Wfr, bias, xgA, xgB, hb, hstate, cstate, l, c);
        }
        uint32_t fk0, fk1;
        tf2x32(0u, 42u, 0u, (uint32_t)l, fk0, fk1);
        if (l < 2)
            k_dropout<<<65536, 256, 0, stream>>>(hb, xhi, xlo, nullptr, fk0, fk1);
        else
            k_dropout<<<65536, 256, 0, stream>>>(hb, nullptr, nullptr, xf32, fk0, fk1);
    }
    k_out<<<512, 256, 0, stream>>>(xf32, Wout, bout, out);
}

// Round 14
// 9298.284 us; speedup vs baseline: 1.0556x; 1.0556x over previous
//
#include <hip/hip_runtime.h>
#include <cstdint>
#include <cstddef>

// ---------- small helpers ----------
typedef __bf16 bf16x8 __attribute__((ext_vector_type(8)));
typedef float  f32x4  __attribute__((ext_vector_type(4)));
typedef _Float16 h2 __attribute__((ext_vector_type(2)));

__device__ __forceinline__ float b2f(unsigned short u) {
    union { uint32_t i; float f; } x; x.i = ((uint32_t)u) << 16; return x.f;
}
__device__ __forceinline__ unsigned short f2bf(float f) {
    uint32_t u = __float_as_uint(f);
    uint32_t r = (u + 0x7FFFu + ((u >> 16) & 1u)) >> 16;   // RNE, no NaN in data
    return (unsigned short)r;
}
__device__ __forceinline__ uint32_t packf16(float a, float b) {
    union { _Float16 h[2]; uint32_t u; } x;
    x.h[0] = (_Float16)a; x.h[1] = (_Float16)b; return x.u;
}
__device__ __forceinline__ h2 u2h(uint32_t u) {
    union { uint32_t u; h2 v; } x; x.u = u; return x.v;
}
__device__ __forceinline__ unsigned short f16b(float f) {
    union { _Float16 h; unsigned short u; } x; x.h = (_Float16)f; return x.u;
}

#if __has_builtin(__builtin_amdgcn_fdot2)
#define FDOT2(w, hh, acc) __builtin_amdgcn_fdot2((w), (hh), (acc), false)
#else
__device__ __forceinline__ float fdot2_sw(h2 a, h2 b, float c) {
    return c + (float)a[0] * (float)b[0] + (float)a[1] * (float)b[1];
}
#define FDOT2(w, hh, acc) fdot2_sw((w), (hh), (acc))
#endif

// JAX threefry2x32 (20 rounds), usable host+device
__host__ __device__ inline void tf2x32(uint32_t k0, uint32_t k1,
                                       uint32_t x0, uint32_t x1,
                                       uint32_t& o0, uint32_t& o1) {
    uint32_t ks2 = k0 ^ k1 ^ 0x1BD11BDAu;
#define TF_ROT(x,n) (((x) << (n)) | ((x) >> (32 - (n))))
#define TF_RND(r) { x0 += x1; x1 = TF_ROT(x1, r); x1 ^= x0; }
    x0 += k0; x1 += k1;
    TF_RND(13) TF_RND(15) TF_RND(26) TF_RND(6)
    x0 += k1; x1 += ks2 + 1u;
    TF_RND(17) TF_RND(29) TF_RND(16) TF_RND(24)
    x0 += ks2; x1 += k0 + 2u;
    TF_RND(13) TF_RND(15) TF_RND(26) TF_RND(6)
    x0 += k0; x1 += k1 + 3u;
    TF_RND(17) TF_RND(29) TF_RND(16) TF_RND(24)
    x0 += k1; x1 += ks2 + 4u;
    TF_RND(13) TF_RND(15) TF_RND(26) TF_RND(6)
    x0 += ks2; x1 += k0 + 5u;
    o0 = x0; o1 = x1;
#undef TF_RND
#undef TF_ROT
}

// ---------- constants ----------
#define BATCH 32
#define TSAMP 524288
#define FRAMES 1024
#define HID 256
#define GATES 1024            // 4*HID
#define MROWS 32768           // BATCH*FRAMES
#define NCLS 29
#define NMASK 16777216u       // 32*1024*512
#define TCH 256               // time chunk
#define NCHUNK 4

// ---------- stats: per-batch mean / 1/(std+eps) ----------
__global__ __launch_bounds__(256) void k_stats1(const float* __restrict__ sig,
                                                float* __restrict__ psum,
                                                float* __restrict__ psq) {
    int blk = blockIdx.x;               // 1024 blocks, 32 per batch
    int tid = threadIdx.x;
    size_t base = (size_t)blk * 16384;
    float s = 0.f, q = 0.f;
    for (int i = 0; i < 16; ++i) {
        float4 v = *reinterpret_cast<const float4*>(sig + base + ((size_t)i * 256 + tid) * 4);
        s += v.x + v.y + v.z + v.w;
        q += v.x * v.x + v.y * v.y + v.z * v.z + v.w * v.w;
    }
    __shared__ float ls[4], lq[4];
    int w = tid >> 6, lane = tid & 63;
    for (int m = 32; m; m >>= 1) { s += __shfl_down(s, m); q += __shfl_down(q, m); }
    if (lane == 0) { ls[w] = s; lq[w] = q; }
    __syncthreads();
    if (tid == 0) {
        psum[blk] = ls[0] + ls[1] + ls[2] + ls[3];
        psq[blk]  = lq[0] + lq[1] + lq[2] + lq[3];
    }
}

__global__ __launch_bounds__(1024) void k_stats2(const float* __restrict__ psum,
                                                 const float* __restrict__ psq,
                                                 float* __restrict__ mu,
                                                 float* __restrict__ rstd) {
    int tid = threadIdx.x;              // 1024 = 32 batches * 32 chunks
    float s = psum[tid], q = psq[tid];
    for (int m = 16; m; m >>= 1) { s += __shfl_down(s, m); q += __shfl_down(q, m); }
    if ((tid & 31) == 0) {
        int b = tid >> 5;
        float m_ = s * (1.f / (float)TSAMP);
        float v  = q * (1.f / (float)TSAMP) - m_ * m_;
        float sd = sqrtf(fmaxf(v, 0.f));
        mu[b] = m_;
        rstd[b] = 1.f / (sd + 1e-8f);
    }
}

// ---------- normalize + frame -> bf16 hi/lo pair [32768][512] ----------
__global__ __launch_bounds__(256) void k_norm(const float* __restrict__ sig,
                                              const float* __restrict__ mu,
                                              const float* __restrict__ rstd,
                                              unsigned short* __restrict__ xh,
                                              unsigned short* __restrict__ xl) {
    size_t gid = (size_t)blockIdx.x * 256 + threadIdx.x;   // 4194304 threads, 4 elems each
    int b = (int)(gid >> 17);
    float m = mu[b], r = rstd[b];
    float4 v = *reinterpret_cast<const float4*>(sig + gid * 4);
    float f0 = (v.x - m) * r, f1 = (v.y - m) * r, f2 = (v.z - m) * r, f3 = (v.w - m) * r;
    ushort4 oh, ol;
    oh.x = f2bf(f0); ol.x = f2bf(f0 - b2f(oh.x));
    oh.y = f2bf(f1); ol.y = f2bf(f1 - b2f(oh.y));
    oh.z = f2bf(f2); ol.z = f2bf(f2 - b2f(oh.z));
    oh.w = f2bf(f3); ol.w = f2bf(f3 - b2f(oh.w));
    *reinterpret_cast<ushort4*>(xh + gid * 4) = oh;
    *reinterpret_cast<ushort4*>(xl + gid * 4) = ol;
}

// ---------- weight prep: Wih transpose + hi/lo split ----------
__global__ __launch_bounds__(256) void k_wih_t(const float* __restrict__ Wih,
                                               unsigned short* __restrict__ WTh,
                                               unsigned short* __restrict__ WTl) {
    size_t gid = (size_t)blockIdx.x * 256 + threadIdx.x;   // 3145728
    int k = (int)(gid & 511);
    int n = (int)((gid >> 9) & 1023);
    int ld = (int)(gid >> 19);
    float w = Wih[((size_t)ld * 512 + k) * 1024 + n];
    unsigned short h = f2bf(w);
    WTh[gid] = h;
    WTl[gid] = f2bf(w - b2f(h));
}

// ---------- weight prep: Whh -> packed fp16, uint4 layout [ld][kg=32][col=1024] ----------
// uint4 component j holds kpair (k = 8*kg + 2j, 8*kg + 2j + 1) of column col.
__global__ __launch_bounds__(256) void k_wkm4(const float* __restrict__ W,
                                              uint4* __restrict__ Wk4) {
    uint32_t gid = blockIdx.x * 256u + threadIdx.x;        // 196608
    int col = (int)(gid & 1023);
    int kg  = (int)((gid >> 10) & 31);
    int ld  = (int)(gid >> 15);
    const float* base = W + (size_t)ld * 256 * 1024 + col;
    uint4 v;
    v.x = packf16(base[(size_t)(8 * kg + 0) * 1024], base[(size_t)(8 * kg + 1) * 1024]);
    v.y = packf16(base[(size_t)(8 * kg + 2) * 1024], base[(size_t)(8 * kg + 3) * 1024]);
    v.z = packf16(base[(size_t)(8 * kg + 4) * 1024], base[(size_t)(8 * kg + 5) * 1024]);
    v.w = packf16(base[(size_t)(8 * kg + 6) * 1024], base[(size_t)(8 * kg + 7) * 1024]);
    Wk4[gid] = v;
}

// ---------- chunked input GEMM (split-bf16 MFMA, fp32 out) ----------
__global__ __launch_bounds__(256) void k_gemm_chunk(const unsigned short* __restrict__ Ah,
                                                    const unsigned short* __restrict__ Al,
                                                    const unsigned short* __restrict__ BTh,
                                                    const unsigned short* __restrict__ BTl,
                                                    float* __restrict__ C,
                                                    int t0) {
    __shared__ __align__(16) unsigned short Ahs[128][40];
    __shared__ __align__(16) unsigned short Als[128][40];
    __shared__ __align__(16) unsigned short Bhs[128][40];
    __shared__ __align__(16) unsigned short Bls[128][40];
    const int tid = threadIdx.x;
    const int tm = blockIdx.y * 128;     // gridDim.y = 64  (8192 chunk rows)
    const int tn = blockIdx.x * 128;     // gridDim.x = 8   (1024 gate cols)
    const int lane = tid & 63, w = tid >> 6;
    const int wr = w >> 1, wc = w & 1;
    const int l15 = lane & 15, lk = (lane >> 4) * 8;
    f32x4 acc[4][4];
    for (int i = 0; i < 4; ++i)
        for (int j = 0; j < 4; ++j)
            acc[i][j] = (f32x4){0.f, 0.f, 0.f, 0.f};
    const int srow = tid >> 1, scol = (tid & 1) * 16;
    const int rg = tm + srow;
    const size_t am = (size_t)((rg >> 8) * 1024 + t0 + (rg & 255)) * 512;
    const size_t bm = (size_t)(tn + srow) * 512;
    for (int kt = 0; kt < 512; kt += 32) {
        *reinterpret_cast<uint4*>(&Ahs[srow][scol])     = *reinterpret_cast<const uint4*>(&Ah[am + kt + scol]);
        *reinterpret_cast<uint4*>(&Ahs[srow][scol + 8]) = *reinterpret_cast<const uint4*>(&Ah[am + kt + scol + 8]);
        *reinterpret_cast<uint4*>(&Als[srow][scol])     = *reinterpret_cast<const uint4*>(&Al[am + kt + scol]);
        *reinterpret_cast<uint4*>(&Als[srow][scol + 8]) = *reinterpret_cast<const uint4*>(&Al[am + kt + scol + 8]);
        *reinterpret_cast<uint4*>(&Bhs[srow][scol])     = *reinterpret_cast<const uint4*>(&BTh[bm + kt + scol]);
        *reinterpret_cast<uint4*>(&Bhs[srow][scol + 8]) = *reinterpret_cast<const uint4*>(&BTh[bm + kt + scol + 8]);
        *reinterpret_cast<uint4*>(&Bls[srow][scol])     = *reinterpret_cast<const uint4*>(&BTl[bm + kt + scol]);
        *reinterpret_cast<uint4*>(&Bls[srow][scol + 8]) = *reinterpret_cast<const uint4*>(&BTl[bm + kt + scol + 8]);
        __syncthreads();
        bf16x8 afh[4], afl[4], bfh[4], bfl[4];
        for (int m = 0; m < 4; ++m) {
            afh[m] = *reinterpret_cast<const bf16x8*>(&Ahs[wr * 64 + m * 16 + l15][lk]);
            afl[m] = *reinterpret_cast<const bf16x8*>(&Als[wr * 64 + m * 16 + l15][lk]);
        }
        for (int n = 0; n < 4; ++n) {
            bfh[n] = *reinterpret_cast<const bf16x8*>(&Bhs[wc * 64 + n * 16 + l15][lk]);
            bfl[n] = *reinterpret_cast<const bf16x8*>(&Bls[wc * 64 + n * 16 + l15][lk]);
        }
        for (int m = 0; m < 4; ++m)
            for (int n = 0; n < 4; ++n) {
                acc[m][n] = __builtin_amdgcn_mfma_f32_16x16x32_bf16(afh[m], bfh[n], acc[m][n], 0, 0, 0);
                acc[m][n] = __builtin_amdgcn_mfma_f32_16x16x32_bf16(afl[m], bfh[n], acc[m][n], 0, 0, 0);
                acc[m][n] = __builtin_amdgcn_mfma_f32_16x16x32_bf16(afh[m], bfl[n], acc[m][n], 0, 0, 0);
            }
        __syncthreads();
    }
    const int rbase = tm + wr * 64 + (lane >> 4) * 4;
    const int cbase = tn + wc * 64 + l15;
    for (int m = 0; m < 4; ++m)
        for (int n = 0; n < 4; ++n)
            for (int r = 0; r < 4; ++r) {
                int row = rbase + m * 16 + r;
                int col = cbase + n * 16;
                C[(size_t)row * 1024 + col] = acc[m][n][r];
            }
}

// ---------- LSTM scan: one block per (dir,batch); 1024 threads, 16 waves ----------
// amdgpu_waves_per_eu(4,4): force the allocator to the TRUE occupancy (132 KB LDS
// already limits to 1 block/CU = 4 waves/EU) -> 128-VGPR budget. Rounds 9-11/13
// showed the default heuristic caps 1024-thread kernels at 64 VGPRs and
// remats/spills any weight array. Tiering sized to fit the 128 budget:
//   kg  0..11 (48 dwords): REGISTERS, pinned (demand ~110 < 128)
//   kg 12..19: LDS [kg][col] uint4 (128 KB; r9-measured 0 bank conflicts)
//   kg 20..31: streamed from L2 (192 KB/step, HALF of r9), 3 batches of 4
//              (bounds in-flight regs), zo blocks LICM hoisting.
__global__ __launch_bounds__(1024)
__attribute__((amdgpu_waves_per_eu(4, 4)))
void k_scan8(const uint4* __restrict__ Wk4,  // [ld][32][1024]
             const float* __restrict__ bias,
             const float* __restrict__ xgA,  // fwd [32][256][1024]
             const float* __restrict__ xgB,  // bwd [32][256][1024]
             float* __restrict__ hout,
             float* __restrict__ hstate,     // [64][256]
             float* __restrict__ cstate,     // [64][256]
             int layer, int chunk) {
    const int g = blockIdx.x;                   // 0..63
    const int d = g >> 5, b = g & 31;
    const int tid = threadIdx.x;                // 0..1023 == gate column
    const int ld = layer * 2 + d;

    __shared__ __align__(16) uint4 Wl4[8 * 1024];          // 128 KB: [kg-12][col]
    __shared__ __align__(16) float gbuf[GATES];            // 4 KB
    __shared__ __align__(16) unsigned short hh_u16[HID];   // h as fp16, 512 B

    const uint4* W = Wk4 + (size_t)ld * 32 * 1024;

    // ---- stage LDS kg 12..19 (coalesced both sides) ----
    #pragma unroll
    for (int kg = 0; kg < 8; ++kg)
        Wl4[kg * 1024 + tid] = W[(size_t)(12 + kg) * 1024 + tid];
    // ---- stage register kg 0..11 (48 dwords), pinned resident ----
    uint4 wreg[12];
    #pragma unroll
    for (int kg = 0; kg < 12; ++kg)
        wreg[kg] = W[(size_t)kg * 1024 + tid];
    #pragma unroll
    for (int kg = 0; kg < 12; ++kg)
        asm volatile("" : "+v"(wreg[kg].x), "+v"(wreg[kg].y),
                          "+v"(wreg[kg].z), "+v"(wreg[kg].w));

    const float bcol = bias[(size_t)ld * 1024 + tid];
    const int gate = tid >> 8;                  // wave-uniform (4 waves per gate)

    float creg = 0.f, hreg = 0.f;
    if (tid < HID) {
        if (chunk != 0) {
            hreg = hstate[(size_t)g * 256 + tid];
            creg = cstate[(size_t)g * 256 + tid];
        }
        hh_u16[tid] = f16b(hreg);
    }
    __syncthreads();

    const float* xbase = (d ? xgB : xgA) + (size_t)b * TCH * 1024;
    const uint4* wst = W + (size_t)20 * 1024 + tid;        // streamed kg 20..31
    const uint4* hh4 = reinterpret_cast<const uint4*>(hh_u16);

    const int tl0 = d ? (TCH - 1) : 0, tstep = d ? -1 : 1;
    float xg = xbase[(size_t)tl0 * 1024 + tid];
    float hprev = 0.f;                                     // pending hout value
    int   tgprev = -1;

    for (int sl = 0; sl < TCH; ++sl) {
        float xgn = xg;
        if (sl + 1 < TCH)
            xgn = xbase[(size_t)(tl0 + tstep * (sl + 1)) * 1024 + tid];

        uint32_t zo = 0;
        asm volatile("" : "+v"(zo));           // opaque 0: loads stay in the loop

        float a0 = 0.f, a1 = 0.f, a2 = 0.f, a3 = 0.f;

        // issue stream batch 1 (kg 20..23)
        uint4 s0 = wst[(size_t)0 * 1024 + zo];
        uint4 s1 = wst[(size_t)1 * 1024 + zo];
        uint4 s2 = wst[(size_t)2 * 1024 + zo];
        uint4 s3 = wst[(size_t)3 * 1024 + zo];

        // register tier: kg 0..11 (long VALU stretch hides stream latency)
        #pragma unroll
        for (int kg = 0; kg < 12; ++kg) {
            uint4 hv = hh4[kg];
            uint4 wv = wreg[kg];
            a0 = FDOT2(u2h(wv.x), u2h(hv.x), a0);
            a1 = FDOT2(u2h(wv.y), u2h(hv.y), a1);
            a2 = FDOT2(u2h(wv.z), u2h(hv.z), a2);
            a3 = FDOT2(u2h(wv.w), u2h(hv.w), a3);
        }

        // issue stream batch 2 (kg 24..27)
        uint4 s4 = wst[(size_t)4 * 1024 + zo];
        uint4 s5 = wst[(size_t)5 * 1024 + zo];
        uint4 s6 = wst[(size_t)6 * 1024 + zo];
        uint4 s7 = wst[(size_t)7 * 1024 + zo];

        // LDS tier: kg 12..19
        #pragma unroll
        for (int kg = 0; kg < 8; ++kg) {
            uint4 hv = hh4[12 + kg];
            uint4 wv = Wl4[kg * 1024 + tid + zo];
            a0 = FDOT2(u2h(wv.x), u2h(hv.x), a0);
            a1 = FDOT2(u2h(wv.y), u2h(hv.y), a1);
            a2 = FDOT2(u2h(wv.z), u2h(hv.z), a2);
            a3 = FDOT2(u2h(wv.w), u2h(hv.w), a3);
        }

        // consume stream batch 1 (kg 20..23)
        {
            uint4 hv;
            hv = hh4[20];
            a0 = FDOT2(u2h(s0.x), u2h(hv.x), a0); a1 = FDOT2(u2h(s0.y), u2h(hv.y), a1);
            a2 = FDOT2(u2h(s0.z), u2h(hv.z), a2); a3 = FDOT2(u2h(s0.w), u2h(hv.w), a3);
            hv = hh4[21];
            a0 = FDOT2(u2h(s1.x), u2h(hv.x), a0); a1 = FDOT2(u2h(s1.y), u2h(hv.y), a1);
            a2 = FDOT2(u2h(s1.z), u2h(hv.z), a2); a3 = FDOT2(u2h(s1.w), u2h(hv.w), a3);
            hv = hh4[22];
            a0 = FDOT2(u2h(s2.x), u2h(hv.x), a0); a1 = FDOT2(u2h(s2.y), u2h(hv.y), a1);
            a2 = FDOT2(u2h(s2.z), u2h(hv.z), a2); a3 = FDOT2(u2h(s2.w), u2h(hv.w), a3);
            hv = hh4[23];
            a0 = FDOT2(u2h(s3.x), u2h(hv.x), a0); a1 = FDOT2(u2h(s3.y), u2h(hv.y), a1);
            a2 = FDOT2(u2h(s3.z), u2h(hv.z), a2); a3 = FDOT2(u2h(s3.w), u2h(hv.w), a3);
        }

        // issue stream batch 3 (kg 28..31)
        uint4 s8  = wst[(size_t)8 * 1024 + zo];
        uint4 s9  = wst[(size_t)9 * 1024 + zo];
        uint4 s10 = wst[(size_t)10 * 1024 + zo];
        uint4 s11 = wst[(size_t)11 * 1024 + zo];

        // consume stream batch 2 (kg 24..27)
        {
            uint4 hv;
            hv = hh4[24];
            a0 = FDOT2(u2h(s4.x), u2h(hv.x), a0); a1 = FDOT2(u2h(s4.y), u2h(hv.y), a1);
            a2 = FDOT2(u2h(s4.z), u2h(hv.z), a2); a3 = FDOT2(u2h(s4.w), u2h(hv.w), a3);
            hv = hh4[25];
            a0 = FDOT2(u2h(s5.x), u2h(hv.x), a0); a1 = FDOT2(u2h(s5.y), u2h(hv.y), a1);
            a2 = FDOT2(u2h(s5.z), u2h(hv.z), a2); a3 = FDOT2(u2h(s5.w), u2h(hv.w), a3);
            hv = hh4[26];
            a0 = FDOT2(u2h(s6.x), u2h(hv.x), a0); a1 = FDOT2(u2h(s6.y), u2h(hv.y), a1);
            a2 = FDOT2(u2h(s6.z), u2h(hv.z), a2); a3 = FDOT2(u2h(s6.w), u2h(hv.w), a3);
            hv = hh4[27];
            a0 = FDOT2(u2h(s7.x), u2h(hv.x), a0); a1 = FDOT2(u2h(s7.y), u2h(hv.y), a1);
            a2 = FDOT2(u2h(s7.z), u2h(hv.z), a2); a3 = FDOT2(u2h(s7.w), u2h(hv.w), a3);
        }
        // consume stream batch 3 (kg 28..31)
        {
            uint4 hv;
            hv = hh4[28];
            a0 = FDOT2(u2h(s8.x), u2h(hv.x), a0);  a1 = FDOT2(u2h(s8.y), u2h(hv.y), a1);
            a2 = FDOT2(u2h(s8.z), u2h(hv.z), a2);  a3 = FDOT2(u2h(s8.w), u2h(hv.w), a3);
            hv = hh4[29];
            a0 = FDOT2(u2h(s9.x), u2h(hv.x), a0);  a1 = FDOT2(u2h(s9.y), u2h(hv.y), a1);
            a2 = FDOT2(u2h(s9.z), u2h(hv.z), a2);  a3 = FDOT2(u2h(s9.w), u2h(hv.w), a3);
            hv = hh4[30];
            a0 = FDOT2(u2h(s10.x), u2h(hv.x), a0); a1 = FDOT2(u2h(s10.y), u2h(hv.y), a1);
            a2 = FDOT2(u2h(s10.z), u2h(hv.z), a2); a3 = FDOT2(u2h(s10.w), u2h(hv.w), a3);
            hv = hh4[31];
            a0 = FDOT2(u2h(s11.x), u2h(hv.x), a0); a1 = FDOT2(u2h(s11.y), u2h(hv.y), a1);
            a2 = FDOT2(u2h(s11.z), u2h(hv.z), a2); a3 = FDOT2(u2h(s11.w), u2h(hv.w), a3);
        }

        float gv = (a0 + a1) + (a2 + a3) + bcol + xg;
        gbuf[tid] = (gate == 2) ? tanhf(gv) : 1.f / (1.f + expf(-gv));
        __syncthreads();

        if (tid < HID) {
            float iv = gbuf[tid], fv = gbuf[256 + tid];
            float gg = gbuf[512 + tid], ov = gbuf[768 + tid];
            creg = fv * creg + iv * gg;
            hreg = ov * tanhf(creg);
            hh_u16[tid] = f16b(hreg);
            const int sgl = chunk * TCH + sl;
            tgprev = d ? (FRAMES - 1 - sgl) : sgl;
            hprev = hreg;
        }
        __syncthreads();
        // deferred global store: ack drains under the next dot phase
        if (tid < HID)
            hout[((size_t)(d * BATCH + b) * FRAMES + tgprev) * HID + tid] = hprev;
        xg = xgn;
    }
    if (tid < HID) {
        hstate[(size_t)g * 256 + tid] = hreg;
        cstate[(size_t)g * 256 + tid] = creg;
    }
}

// ---------- dropout(0.5) + ReLU + concat, JAX partitionable threefry ----------
__global__ __launch_bounds__(256) void k_dropout(const float* __restrict__ h,
                                                 unsigned short* __restrict__ xh,  // may be null
                                                 unsigned short* __restrict__ xl,  // may be null
                                                 float* __restrict__ xf,           // may be null
                                                 uint32_t fk0, uint32_t fk1) {
    uint32_t i = blockIdx.x * 256u + threadIdx.x;    // grid 65536 -> NMASK threads
    uint32_t o0, o1;
    tf2x32(fk0, fk1, 0u, i, o0, o1);
    uint32_t bits = o0 ^ o1;
    uint32_t f = i & 511u;
    uint32_t t = (i >> 9) & 1023u;
    uint32_t b = i >> 19;                            // 0..31
    uint32_t dv = f >> 8, n = f & 255u;
    float v = h[(((size_t)dv * BATCH + b) * FRAMES + t) * HID + n];
    float o = (((bits >> 31) == 0u) && v > 0.f) ? 2.f * v : 0.f;
    if (xh != nullptr) {
        unsigned short hb_ = f2bf(o);
        xh[i] = hb_;
        xl[i] = f2bf(o - b2f(hb_));
    }
    if (xf != nullptr) xf[i] = o;
}

// ---------- output projection: out[32768][29] = Xf[32768][512] @ Wout + bout ----------
__global__ __launch_bounds__(256) void k_out(const float* __restrict__ xf,
                                             const float* __restrict__ Wout,
                                             const float* __restrict__ bout,
                                             float* __restrict__ out) {
    __shared__ __align__(16) float Xs[64][68];
    const int tid = threadIdx.x;
    const int r = tid & 63, cg = tid >> 6;           // 4 col-groups of 8 (last has 5)
    const int row0 = blockIdx.x * 64;
    float acc[8] = {0.f, 0.f, 0.f, 0.f, 0.f, 0.f, 0.f, 0.f};
    for (int kc = 0; kc < 512; kc += 64) {
        int sr = tid >> 2, sc = (tid & 3) * 16;
        const float* src = xf + (size_t)(row0 + sr) * 512 + kc + sc;
        *reinterpret_cast<float4*>(&Xs[sr][sc])      = *reinterpret_cast<const float4*>(src);
        *reinterpret_cast<float4*>(&Xs[sr][sc + 4])  = *reinterpret_cast<const float4*>(src + 4);
        *reinterpret_cast<float4*>(&Xs[sr][sc + 8])  = *reinterpret_cast<const float4*>(src + 8);
        *reinterpret_cast<float4*>(&Xs[sr][sc + 12]) = *reinterpret_cast<const float4*>(src + 12);
        __syncthreads();
        for (int k = 0; k < 64; ++k) {
            float xv = Xs[r][k];
            const float* wr = Wout + (size_t)(kc + k) * NCLS + cg * 8;
            #pragma unroll
            for (int cc = 0; cc < 8; ++cc)
                if (cg * 8 + cc < NCLS) acc[cc] = fmaf(xv, wr[cc], acc[cc]);
        }
        __syncthreads();
    }
    for (int cc = 0; cc < 8; ++cc) {
        int col = cg * 8 + cc;
        if (col < NCLS) out[(size_t)(row0 + r) * NCLS + col] = acc[cc] + bout[col];
    }
}

// ---------- launch ----------
extern "C" void kernel_launch(void* const* d_in, const int* in_sizes, int n_in,
                              void* d_out, int out_size, void* d_ws, size_t ws_size,
                              hipStream_t stream) {
    const float* sig  = (const float*)d_in[0];
    const float* Wih  = (const float*)d_in[1];
    const float* Whh  = (const float*)d_in[2];
    const float* bias = (const float*)d_in[3];
    const float* Wout = (const float*)d_in[4];
    const float* bout = (const float*)d_in[5];
    float* out = (float*)d_out;

    char* ws = (char*)d_ws;
    size_t off = 0;
    auto alloc = [&](size_t bytes) -> void* {
        void* p = ws + off;
        off += (bytes + 255) & ~(size_t)255;
        return p;
    };
    float* psum           = (float*)alloc(1024 * 4);
    float* psq            = (float*)alloc(1024 * 4);
    float* mu             = (float*)alloc(32 * 4);
    float* rstd           = (float*)alloc(32 * 4);
    unsigned short* WThi  = (unsigned short*)alloc((size_t)6 * 1024 * 512 * 2);     // 6.3 MB
    unsigned short* WTlo  = (unsigned short*)alloc((size_t)6 * 1024 * 512 * 2);     // 6.3 MB
    uint4* Wk4            = (uint4*)alloc((size_t)6 * 32 * 1024 * 16);              // 3.1 MB
    unsigned short* xhi   = (unsigned short*)alloc((size_t)MROWS * 512 * 2);        // 33.5 MB
    unsigned short* xlo   = (unsigned short*)alloc((size_t)MROWS * 512 * 2);        // 33.5 MB
    float* xgA            = (float*)alloc((size_t)BATCH * TCH * 1024 * 4);          // 33.5 MB
    float* xgB            = (float*)alloc((size_t)BATCH * TCH * 1024 * 4);          // 33.5 MB
    float* hb             = (float*)alloc((size_t)2 * BATCH * FRAMES * HID * 4);    // 67 MB
    float* hstate         = (float*)alloc((size_t)64 * HID * 4);
    float* cstate         = (float*)alloc((size_t)64 * HID * 4);
    // Total ~218 MB (proven layout).
    float* xf32           = (float*)xhi;   // layer-2 fp32 activations overlay dead xhi/xlo

    k_stats1<<<1024, 256, 0, stream>>>(sig, psum, psq);
    k_stats2<<<1, 1024, 0, stream>>>(psum, psq, mu, rstd);
    k_norm<<<16384, 256, 0, stream>>>(sig, mu, rstd, xhi, xlo);
    k_wih_t<<<12288, 256, 0, stream>>>(Wih, WThi, WTlo);
    k_wkm4<<<768, 256, 0, stream>>>(Whh, Wk4);

    for (int l = 0; l < 3; ++l) {
        const unsigned short* Bh0 = WThi + (size_t)(l * 2 + 0) * 1024 * 512;
        const unsigned short* Bl0 = WTlo + (size_t)(l * 2 + 0) * 1024 * 512;
        const unsigned short* Bh1 = WThi + (size_t)(l * 2 + 1) * 1024 * 512;
        const unsigned short* Bl1 = WTlo + (size_t)(l * 2 + 1) * 1024 * 512;
        for (int c = 0; c < NCHUNK; ++c) {
            dim3 gg(8, 64);
            int t0f = c * TCH;
            int t0b = (NCHUNK - 1 - c) * TCH;
            k_gemm_chunk<<<gg, 256, 0, stream>>>(xhi, xlo, Bh0, Bl0, xgA, t0f);
            k_gemm_chunk<<<gg, 256, 0, stream>>>(xhi, xlo, Bh1, Bl1, xgB, t0b);
            k_scan8<<<64, 1024, 0, stream>>>(Wk4, bias, xgA, xgB, hb, hstate, cstate, l, c);
        }
        uint32_t fk0, fk1;
        tf2x32(0u, 42u, 0u, (uint32_t)l, fk0, fk1);
        if (l < 2)
            k_dropout<<<65536, 256, 0, stream>>>(hb, xhi, xlo, nullptr, fk0, fk1);
        else
            k_dropout<<<65536, 256, 0, stream>>>(hb, nullptr, nullptr, xf32, fk0, fk1);
    }
    k_out<<<512, 256, 0, stream>>>(xf32, Wout, bout, out);
}

// Round 15
// 7513.107 us; speedup vs baseline: 1.3064x; 1.2376x over previous
//
#include <hip/hip_runtime.h>
#include <cstdint>
#include <cstddef>

// ---------- small helpers ----------
typedef __bf16 bf16x8 __attribute__((ext_vector_type(8)));
typedef float  f32x4  __attribute__((ext_vector_type(4)));
typedef _Float16 h2 __attribute__((ext_vector_type(2)));

__device__ __forceinline__ float b2f(unsigned short u) {
    union { uint32_t i; float f; } x; x.i = ((uint32_t)u) << 16; return x.f;
}
__device__ __forceinline__ unsigned short f2bf(float f) {
    uint32_t u = __float_as_uint(f);
    uint32_t r = (u + 0x7FFFu + ((u >> 16) & 1u)) >> 16;   // RNE, no NaN in data
    return (unsigned short)r;
}
__device__ __forceinline__ uint32_t packf16(float a, float b) {
    union { _Float16 h[2]; uint32_t u; } x;
    x.h[0] = (_Float16)a; x.h[1] = (_Float16)b; return x.u;
}
__device__ __forceinline__ h2 u2h(uint32_t u) {
    union { uint32_t u; h2 v; } x; x.u = u; return x.v;
}
__device__ __forceinline__ unsigned short f16b(float f) {
    union { _Float16 h; unsigned short u; } x; x.h = (_Float16)f; return x.u;
}

#if __has_builtin(__builtin_amdgcn_fdot2)
#define FDOT2(w, hh, acc) __builtin_amdgcn_fdot2((w), (hh), (acc), false)
#else
__device__ __forceinline__ float fdot2_sw(h2 a, h2 b, float c) {
    return c + (float)a[0] * (float)b[0] + (float)a[1] * (float)b[1];
}
#define FDOT2(w, hh, acc) fdot2_sw((w), (hh), (acc))
#endif

// JAX threefry2x32 (20 rounds), usable host+device
__host__ __device__ inline void tf2x32(uint32_t k0, uint32_t k1,
                                       uint32_t x0, uint32_t x1,
                                       uint32_t& o0, uint32_t& o1) {
    uint32_t ks2 = k0 ^ k1 ^ 0x1BD11BDAu;
#define TF_ROT(x,n) (((x) << (n)) | ((x) >> (32 - (n))))
#define TF_RND(r) { x0 += x1; x1 = TF_ROT(x1, r); x1 ^= x0; }
    x0 += k0; x1 += k1;
    TF_RND(13) TF_RND(15) TF_RND(26) TF_RND(6)
    x0 += k1; x1 += ks2 + 1u;
    TF_RND(17) TF_RND(29) TF_RND(16) TF_RND(24)
    x0 += ks2; x1 += k0 + 2u;
    TF_RND(13) TF_RND(15) TF_RND(26) TF_RND(6)
    x0 += k0; x1 += k1 + 3u;
    TF_RND(17) TF_RND(29) TF_RND(16) TF_RND(24)
    x0 += k1; x1 += ks2 + 4u;
    TF_RND(13) TF_RND(15) TF_RND(26) TF_RND(6)
    x0 += ks2; x1 += k0 + 5u;
    o0 = x0; o1 = x1;
#undef TF_RND
#undef TF_ROT
}

// ---------- constants ----------
#define BATCH 32
#define TSAMP 524288
#define FRAMES 1024
#define HID 256
#define GATES 1024            // 4*HID
#define MROWS 32768           // BATCH*FRAMES
#define NCLS 29
#define NMASK 16777216u       // 32*1024*512
#define TCH 256               // time chunk
#define NCHUNK 4

// ---------- stats: per-batch mean / 1/(std+eps) ----------
__global__ __launch_bounds__(256) void k_stats1(const float* __restrict__ sig,
                                                float* __restrict__ psum,
                                                float* __restrict__ psq) {
    int blk = blockIdx.x;               // 1024 blocks, 32 per batch
    int tid = threadIdx.x;
    size_t base = (size_t)blk * 16384;
    float s = 0.f, q = 0.f;
    for (int i = 0; i < 16; ++i) {
        float4 v = *reinterpret_cast<const float4*>(sig + base + ((size_t)i * 256 + tid) * 4);
        s += v.x + v.y + v.z + v.w;
        q += v.x * v.x + v.y * v.y + v.z * v.z + v.w * v.w;
    }
    __shared__ float ls[4], lq[4];
    int w = tid >> 6, lane = tid & 63;
    for (int m = 32; m; m >>= 1) { s += __shfl_down(s, m); q += __shfl_down(q, m); }
    if (lane == 0) { ls[w] = s; lq[w] = q; }
    __syncthreads();
    if (tid == 0) {
        psum[blk] = ls[0] + ls[1] + ls[2] + ls[3];
        psq[blk]  = lq[0] + lq[1] + lq[2] + lq[3];
    }
}

__global__ __launch_bounds__(1024) void k_stats2(const float* __restrict__ psum,
                                                 const float* __restrict__ psq,
                                                 float* __restrict__ mu,
                                                 float* __restrict__ rstd) {
    int tid = threadIdx.x;              // 1024 = 32 batches * 32 chunks
    float s = psum[tid], q = psq[tid];
    for (int m = 16; m; m >>= 1) { s += __shfl_down(s, m); q += __shfl_down(q, m); }
    if ((tid & 31) == 0) {
        int b = tid >> 5;
        float m_ = s * (1.f / (float)TSAMP);
        float v  = q * (1.f / (float)TSAMP) - m_ * m_;
        float sd = sqrtf(fmaxf(v, 0.f));
        mu[b] = m_;
        rstd[b] = 1.f / (sd + 1e-8f);
    }
}

// ---------- normalize + frame -> bf16 hi/lo pair [32768][512] ----------
__global__ __launch_bounds__(256) void k_norm(const float* __restrict__ sig,
                                              const float* __restrict__ mu,
                                              const float* __restrict__ rstd,
                                              unsigned short* __restrict__ xh,
                                              unsigned short* __restrict__ xl) {
    size_t gid = (size_t)blockIdx.x * 256 + threadIdx.x;   // 4194304 threads, 4 elems each
    int b = (int)(gid >> 17);
    float m = mu[b], r = rstd[b];
    float4 v = *reinterpret_cast<const float4*>(sig + gid * 4);
    float f0 = (v.x - m) * r, f1 = (v.y - m) * r, f2 = (v.z - m) * r, f3 = (v.w - m) * r;
    ushort4 oh, ol;
    oh.x = f2bf(f0); ol.x = f2bf(f0 - b2f(oh.x));
    oh.y = f2bf(f1); ol.y = f2bf(f1 - b2f(oh.y));
    oh.z = f2bf(f2); ol.z = f2bf(f2 - b2f(oh.z));
    oh.w = f2bf(f3); ol.w = f2bf(f3 - b2f(oh.w));
    *reinterpret_cast<ushort4*>(xh + gid * 4) = oh;
    *reinterpret_cast<ushort4*>(xl + gid * 4) = ol;
}

// ---------- weight prep: Wih transpose + hi/lo split ----------
__global__ __launch_bounds__(256) void k_wih_t(const float* __restrict__ Wih,
                                               unsigned short* __restrict__ WTh,
                                               unsigned short* __restrict__ WTl) {
    size_t gid = (size_t)blockIdx.x * 256 + threadIdx.x;   // 3145728
    int k = (int)(gid & 511);
    int n = (int)((gid >> 9) & 1023);
    int ld = (int)(gid >> 19);
    float w = Wih[((size_t)ld * 512 + k) * 1024 + n];
    unsigned short h = f2bf(w);
    WTh[gid] = h;
    WTl[gid] = f2bf(w - b2f(h));
}

// ---------- weight prep: Whh -> packed fp16, uint4 layout [ld][kg=32][col=1024] ----------
// uint4 component j holds kpair (k = 8*kg + 2j, 8*kg + 2j + 1) of column col.
__global__ __launch_bounds__(256) void k_wkm4(const float* __restrict__ W,
                                              uint4* __restrict__ Wk4) {
    uint32_t gid = blockIdx.x * 256u + threadIdx.x;        // 196608
    int col = (int)(gid & 1023);
    int kg  = (int)((gid >> 10) & 31);
    int ld  = (int)(gid >> 15);
    const float* base = W + (size_t)ld * 256 * 1024 + col;
    uint4 v;
    v.x = packf16(base[(size_t)(8 * kg + 0) * 1024], base[(size_t)(8 * kg + 1) * 1024]);
    v.y = packf16(base[(size_t)(8 * kg + 2) * 1024], base[(size_t)(8 * kg + 3) * 1024]);
    v.z = packf16(base[(size_t)(8 * kg + 4) * 1024], base[(size_t)(8 * kg + 5) * 1024]);
    v.w = packf16(base[(size_t)(8 * kg + 6) * 1024], base[(size_t)(8 * kg + 7) * 1024]);
    Wk4[gid] = v;
}

// ---------- chunked input GEMM (split-bf16 MFMA, fp32 out) ----------
__global__ __launch_bounds__(256) void k_gemm_chunk(const unsigned short* __restrict__ Ah,
                                                    const unsigned short* __restrict__ Al,
                                                    const unsigned short* __restrict__ BTh,
                                                    const unsigned short* __restrict__ BTl,
                                                    float* __restrict__ C,
                                                    int t0) {
    __shared__ __align__(16) unsigned short Ahs[128][40];
    __shared__ __align__(16) unsigned short Als[128][40];
    __shared__ __align__(16) unsigned short Bhs[128][40];
    __shared__ __align__(16) unsigned short Bls[128][40];
    const int tid = threadIdx.x;
    const int tm = blockIdx.y * 128;     // gridDim.y = 64  (8192 chunk rows)
    const int tn = blockIdx.x * 128;     // gridDim.x = 8   (1024 gate cols)
    const int lane = tid & 63, w = tid >> 6;
    const int wr = w >> 1, wc = w & 1;
    const int l15 = lane & 15, lk = (lane >> 4) * 8;
    f32x4 acc[4][4];
    for (int i = 0; i < 4; ++i)
        for (int j = 0; j < 4; ++j)
            acc[i][j] = (f32x4){0.f, 0.f, 0.f, 0.f};
    const int srow = tid >> 1, scol = (tid & 1) * 16;
    const int rg = tm + srow;
    const size_t am = (size_t)((rg >> 8) * 1024 + t0 + (rg & 255)) * 512;
    const size_t bm = (size_t)(tn + srow) * 512;
    for (int kt = 0; kt < 512; kt += 32) {
        *reinterpret_cast<uint4*>(&Ahs[srow][scol])     = *reinterpret_cast<const uint4*>(&Ah[am + kt + scol]);
        *reinterpret_cast<uint4*>(&Ahs[srow][scol + 8]) = *reinterpret_cast<const uint4*>(&Ah[am + kt + scol + 8]);
        *reinterpret_cast<uint4*>(&Als[srow][scol])     = *reinterpret_cast<const uint4*>(&Al[am + kt + scol]);
        *reinterpret_cast<uint4*>(&Als[srow][scol + 8]) = *reinterpret_cast<const uint4*>(&Al[am + kt + scol + 8]);
        *reinterpret_cast<uint4*>(&Bhs[srow][scol])     = *reinterpret_cast<const uint4*>(&BTh[bm + kt + scol]);
        *reinterpret_cast<uint4*>(&Bhs[srow][scol + 8]) = *reinterpret_cast<const uint4*>(&BTh[bm + kt + scol + 8]);
        *reinterpret_cast<uint4*>(&Bls[srow][scol])     = *reinterpret_cast<const uint4*>(&BTl[bm + kt + scol]);
        *reinterpret_cast<uint4*>(&Bls[srow][scol + 8]) = *reinterpret_cast<const uint4*>(&BTl[bm + kt + scol + 8]);
        __syncthreads();
        bf16x8 afh[4], afl[4], bfh[4], bfl[4];
        for (int m = 0; m < 4; ++m) {
            afh[m] = *reinterpret_cast<const bf16x8*>(&Ahs[wr * 64 + m * 16 + l15][lk]);
            afl[m] = *reinterpret_cast<const bf16x8*>(&Als[wr * 64 + m * 16 + l15][lk]);
        }
        for (int n = 0; n < 4; ++n) {
            bfh[n] = *reinterpret_cast<const bf16x8*>(&Bhs[wc * 64 + n * 16 + l15][lk]);
            bfl[n] = *reinterpret_cast<const bf16x8*>(&Bls[wc * 64 + n * 16 + l15][lk]);
        }
        for (int m = 0; m < 4; ++m)
            for (int n = 0; n < 4; ++n) {
                acc[m][n] = __builtin_amdgcn_mfma_f32_16x16x32_bf16(afh[m], bfh[n], acc[m][n], 0, 0, 0);
                acc[m][n] = __builtin_amdgcn_mfma_f32_16x16x32_bf16(afl[m], bfh[n], acc[m][n], 0, 0, 0);
                acc[m][n] = __builtin_amdgcn_mfma_f32_16x16x32_bf16(afh[m], bfl[n], acc[m][n], 0, 0, 0);
            }
        __syncthreads();
    }
    const int rbase = tm + wr * 64 + (lane >> 4) * 4;
    const int cbase = tn + wc * 64 + l15;
    for (int m = 0; m < 4; ++m)
        for (int n = 0; n < 4; ++n)
            for (int r = 0; r < 4; ++r) {
                int row = rbase + m * 16 + r;
                int col = cbase + n * 16;
                C[(size_t)row * 1024 + col] = acc[m][n][r];
            }
}

// ---------- LSTM scan: one block per (dir,batch); 1024 threads, 16 waves ----------
// EXACT round-9 structure (session-best 548 us/dispatch) with ONE change:
// LDS weight tier 8 -> 9 kg (144 KB; total LDS ~152 KB < 160), shrinking the
// de-facto streamed portion 384 -> 368 KB/step. Allocator model (r9-r14, 6 probes):
// 1024-thread kernels are pinned at 64 VGPRs; "register tiers" always remat to
// per-step L2 loads -- which 16 waves of TLP absorb at ~180 GB/s/CU (2.1 us/step).
__global__ __launch_bounds__(1024, 4) void k_scan5(const uint4* __restrict__ Wk4,  // [ld][32][1024]
                                                   const float* __restrict__ bias,
                                                   const float* __restrict__ xgA,  // fwd [32][256][1024]
                                                   const float* __restrict__ xgB,  // bwd [32][256][1024]
                                                   float* __restrict__ hout,
                                                   float* __restrict__ hstate,     // [64][256]
                                                   float* __restrict__ cstate,     // [64][256]
                                                   int layer, int chunk) {
    const int g = blockIdx.x;                   // 0..63
    const int d = g >> 5, b = g & 31;
    const int tid = threadIdx.x;                // 0..1023 == gate column
    const int ld = layer * 2 + d;

    __shared__ __align__(16) uint4 Wl4[9 * 1024];          // 144 KB: [kg-15][col]
    __shared__ __align__(16) float gbuf[GATES];            // 4 KB
    __shared__ __align__(16) unsigned short hh_u16[HID];   // h as fp16, 512 B

    const uint4* W = Wk4 + (size_t)ld * 32 * 1024;

    // ---- stage LDS kg 15..23 (coalesced both sides) ----
    #pragma unroll
    for (int kg = 0; kg < 9; ++kg)
        Wl4[kg * 1024 + tid] = W[(size_t)(15 + kg) * 1024 + tid];
    // ---- "register" kg 0..14 (compiler will remat; 16-wave TLP absorbs it) ----
    uint4 wreg[15];
    #pragma unroll
    for (int kg = 0; kg < 15; ++kg)
        wreg[kg] = W[(size_t)kg * 1024 + tid];

    const float bcol = bias[(size_t)ld * 1024 + tid];
    const int gate = tid >> 8;                  // wave-uniform (4 waves per gate)

    float creg = 0.f, hreg = 0.f;
    if (tid < HID) {
        if (chunk != 0) {
            hreg = hstate[(size_t)g * 256 + tid];
            creg = cstate[(size_t)g * 256 + tid];
        }
        hh_u16[tid] = f16b(hreg);
    }
    __syncthreads();

    const float* xbase = (d ? xgB : xgA) + (size_t)b * TCH * 1024;
    const uint4* wst = W + (size_t)24 * 1024 + tid;        // streamed kg 24..31
    const uint4* hh4 = reinterpret_cast<const uint4*>(hh_u16);

    const int tl0 = d ? (TCH - 1) : 0, tstep = d ? -1 : 1;
    float xg = xbase[(size_t)tl0 * 1024 + tid];
    float hprev = 0.f;                                     // pending hout value
    int   tgprev = -1;

    for (int sl = 0; sl < TCH; ++sl) {
        float xgn = xg;
        if (sl + 1 < TCH)
            xgn = xbase[(size_t)(tl0 + tstep * (sl + 1)) * 1024 + tid];

        float a0 = 0.f, a1 = 0.f, a2 = 0.f, a3 = 0.f;
        // registers/remat: kg 0..14
        #pragma unroll
        for (int kg = 0; kg < 15; ++kg) {
            uint4 hv = hh4[kg];
            uint4 wv = wreg[kg];
            a0 = FDOT2(u2h(wv.x), u2h(hv.x), a0);
            a1 = FDOT2(u2h(wv.y), u2h(hv.y), a1);
            a2 = FDOT2(u2h(wv.z), u2h(hv.z), a2);
            a3 = FDOT2(u2h(wv.w), u2h(hv.w), a3);
        }
        // LDS: kg 15..23
        #pragma unroll
        for (int kg = 0; kg < 9; ++kg) {
            uint4 hv = hh4[15 + kg];
            uint4 wv = Wl4[kg * 1024 + tid];
            a0 = FDOT2(u2h(wv.x), u2h(hv.x), a0);
            a1 = FDOT2(u2h(wv.y), u2h(hv.y), a1);
            a2 = FDOT2(u2h(wv.z), u2h(hv.z), a2);
            a3 = FDOT2(u2h(wv.w), u2h(hv.w), a3);
        }
        // stream: kg 24..31
        #pragma unroll
        for (int kg = 0; kg < 8; ++kg) {
            uint4 hv = hh4[24 + kg];
            uint4 wv = wst[(size_t)kg * 1024];
            a0 = FDOT2(u2h(wv.x), u2h(hv.x), a0);
            a1 = FDOT2(u2h(wv.y), u2h(hv.y), a1);
            a2 = FDOT2(u2h(wv.z), u2h(hv.z), a2);
            a3 = FDOT2(u2h(wv.w), u2h(hv.w), a3);
        }

        float gv = (a0 + a1) + (a2 + a3) + bcol + xg;
        gbuf[tid] = (gate == 2) ? tanhf(gv) : 1.f / (1.f + expf(-gv));
        __syncthreads();

        if (tid < HID) {
            float iv = gbuf[tid], fv = gbuf[256 + tid];
            float gg = gbuf[512 + tid], ov = gbuf[768 + tid];
            creg = fv * creg + iv * gg;
            hreg = ov * tanhf(creg);
            hh_u16[tid] = f16b(hreg);
            const int sgl = chunk * TCH + sl;
            tgprev = d ? (FRAMES - 1 - sgl) : sgl;
            hprev = hreg;
        }
        __syncthreads();
        // deferred global store: ack drains under the next dot phase
        if (tid < HID)
            hout[((size_t)(d * BATCH + b) * FRAMES + tgprev) * HID + tid] = hprev;
        xg = xgn;
    }
    if (tid < HID) {
        hstate[(size_t)g * 256 + tid] = hreg;
        cstate[(size_t)g * 256 + tid] = creg;
    }
}

// ---------- dropout(0.5) + ReLU + concat, JAX partitionable threefry ----------
__global__ __launch_bounds__(256) void k_dropout(const float* __restrict__ h,
                                                 unsigned short* __restrict__ xh,  // may be null
                                                 unsigned short* __restrict__ xl,  // may be null
                                                 float* __restrict__ xf,           // may be null
                                                 uint32_t fk0, uint32_t fk1) {
    uint32_t i = blockIdx.x * 256u + threadIdx.x;    // grid 65536 -> NMASK threads
    uint32_t o0, o1;
    tf2x32(fk0, fk1, 0u, i, o0, o1);
    uint32_t bits = o0 ^ o1;
    uint32_t f = i & 511u;
    uint32_t t = (i >> 9) & 1023u;
    uint32_t b = i >> 19;                            // 0..31
    uint32_t dv = f >> 8, n = f & 255u;
    float v = h[(((size_t)dv * BATCH + b) * FRAMES + t) * HID + n];
    float o = (((bits >> 31) == 0u) && v > 0.f) ? 2.f * v : 0.f;
    if (xh != nullptr) {
        unsigned short hb_ = f2bf(o);
        xh[i] = hb_;
        xl[i] = f2bf(o - b2f(hb_));
    }
    if (xf != nullptr) xf[i] = o;
}

// ---------- output projection: out[32768][29] = Xf[32768][512] @ Wout + bout ----------
__global__ __launch_bounds__(256) void k_out(const float* __restrict__ xf,
                                             const float* __restrict__ Wout,
                                             const float* __restrict__ bout,
                                             float* __restrict__ out) {
    __shared__ __align__(16) float Xs[64][68];
    const int tid = threadIdx.x;
    const int r = tid & 63, cg = tid >> 6;           // 4 col-groups of 8 (last has 5)
    const int row0 = blockIdx.x * 64;
    float acc[8] = {0.f, 0.f, 0.f, 0.f, 0.f, 0.f, 0.f, 0.f};
    for (int kc = 0; kc < 512; kc += 64) {
        int sr = tid >> 2, sc = (tid & 3) * 16;
        const float* src = xf + (size_t)(row0 + sr) * 512 + kc + sc;
        *reinterpret_cast<float4*>(&Xs[sr][sc])      = *reinterpret_cast<const float4*>(src);
        *reinterpret_cast<float4*>(&Xs[sr][sc + 4])  = *reinterpret_cast<const float4*>(src + 4);
        *reinterpret_cast<float4*>(&Xs[sr][sc + 8])  = *reinterpret_cast<const float4*>(src + 8);
        *reinterpret_cast<float4*>(&Xs[sr][sc + 12]) = *reinterpret_cast<const float4*>(src + 12);
        __syncthreads();
        for (int k = 0; k < 64; ++k) {
            float xv = Xs[r][k];
            const float* wr = Wout + (size_t)(kc + k) * NCLS + cg * 8;
            #pragma unroll
            for (int cc = 0; cc < 8; ++cc)
                if (cg * 8 + cc < NCLS) acc[cc] = fmaf(xv, wr[cc], acc[cc]);
        }
        __syncthreads();
    }
    for (int cc = 0; cc < 8; ++cc) {
        int col = cg * 8 + cc;
        if (col < NCLS) out[(size_t)(row0 + r) * NCLS + col] = acc[cc] + bout[col];
    }
}

// ---------- launch ----------
extern "C" void kernel_launch(void* const* d_in, const int* in_sizes, int n_in,
                              void* d_out, int out_size, void* d_ws, size_t ws_size,
                              hipStream_t stream) {
    const float* sig  = (const float*)d_in[0];
    const float* Wih  = (const float*)d_in[1];
    const float* Whh  = (const float*)d_in[2];
    const float* bias = (const float*)d_in[3];
    const float* Wout = (const float*)d_in[4];
    const float* bout = (const float*)d_in[5];
    float* out = (float*)d_out;

    char* ws = (char*)d_ws;
    size_t off = 0;
    auto alloc = [&](size_t bytes) -> void* {
        void* p = ws + off;
        off += (bytes + 255) & ~(size_t)255;
        return p;
    };
    float* psum           = (float*)alloc(1024 * 4);
    float* psq            = (float*)alloc(1024 * 4);
    float* mu             = (float*)alloc(32 * 4);
    float* rstd           = (float*)alloc(32 * 4);
    unsigned short* WThi  = (unsigned short*)alloc((size_t)6 * 1024 * 512 * 2);     // 6.3 MB
    unsigned short* WTlo  = (unsigned short*)alloc((size_t)6 * 1024 * 512 * 2);     // 6.3 MB
    uint4* Wk4            = (uint4*)alloc((size_t)6 * 32 * 1024 * 16);              // 3.1 MB
    unsigned short* xhi   = (unsigned short*)alloc((size_t)MROWS * 512 * 2);        // 33.5 MB
    unsigned short* xlo   = (unsigned short*)alloc((size_t)MROWS * 512 * 2);        // 33.5 MB
    float* xgA            = (float*)alloc((size_t)BATCH * TCH * 1024 * 4);          // 33.5 MB
    float* xgB            = (float*)alloc((size_t)BATCH * TCH * 1024 * 4);          // 33.5 MB
    float* hb             = (float*)alloc((size_t)2 * BATCH * FRAMES * HID * 4);    // 67 MB
    float* hstate         = (float*)alloc((size_t)64 * HID * 4);
    float* cstate         = (float*)alloc((size_t)64 * HID * 4);
    // Total ~218 MB (proven layout).
    float* xf32           = (float*)xhi;   // layer-2 fp32 activations overlay dead xhi/xlo

    k_stats1<<<1024, 256, 0, stream>>>(sig, psum, psq);
    k_stats2<<<1, 1024, 0, stream>>>(psum, psq, mu, rstd);
    k_norm<<<16384, 256, 0, stream>>>(sig, mu, rstd, xhi, xlo);
    k_wih_t<<<12288, 256, 0, stream>>>(Wih, WThi, WTlo);
    k_wkm4<<<768, 256, 0, stream>>>(Whh, Wk4);

    for (int l = 0; l < 3; ++l) {
        const unsigned short* Bh0 = WThi + (size_t)(l * 2 + 0) * 1024 * 512;
        const unsigned short* Bl0 = WTlo + (size_t)(l * 2 + 0) * 1024 * 512;
        const unsigned short* Bh1 = WThi + (size_t)(l * 2 + 1) * 1024 * 512;
        const unsigned short* Bl1 = WTlo + (size_t)(l * 2 + 1) * 1024 * 512;
        for (int c = 0; c < NCHUNK; ++c) {
            dim3 gg(8, 64);
            int t0f = c * TCH;
            int t0b = (NCHUNK - 1 - c) * TCH;
            k_gemm_chunk<<<gg, 256, 0, stream>>>(xhi, xlo, Bh0, Bl0, xgA, t0f);
            k_gemm_chunk<<<gg, 256, 0, stream>>>(xhi, xlo, Bh1, Bl1, xgB, t0b);
            k_scan5<<<64, 1024, 0, stream>>>(Wk4, bias, xgA, xgB, hb, hstate, cstate, l, c);
        }
        uint32_t fk0, fk1;
        tf2x32(0u, 42u, 0u, (uint32_t)l, fk0, fk1);
        if (l < 2)
            k_dropout<<<65536, 256, 0, stream>>>(hb, xhi, xlo, nullptr, fk0, fk1);
        else
            k_dropout<<<65536, 256, 0, stream>>>(hb, nullptr, nullptr, xf32, fk0, fk1);
    }
    k_out<<<512, 256, 0, stream>>>(xf32, Wout, bout, out);
}